// Round 1
// baseline (877.084 us; speedup 1.0000x reference)
//
#include <hip/hip_runtime.h>
#include <hip/hip_bf16.h>
#include <math.h>

typedef unsigned int uint;
typedef unsigned short ushort;

// ---------- small helpers ----------
__device__ __forceinline__ float bf2f(uint u) {
    return __uint_as_float(u << 16);
}
__device__ __forceinline__ ushort f2bf(float f) {
    uint u = __float_as_uint(f);
    uint rounding = 0x7fffu + ((u >> 16) & 1u);   // round-to-nearest-even
    return (ushort)((u + rounding) >> 16);
}
__device__ __forceinline__ float elu(float x) {
    return x > 0.f ? x : expm1f(x);
}

// ---------- degree histogram ----------
__global__ void count_kernel(const int* __restrict__ dst, int E, int* __restrict__ cnt) {
    int i = blockIdx.x * blockDim.x + threadIdx.x;
    int stride = gridDim.x * blockDim.x;
    for (; i < E; i += stride) atomicAdd(&cnt[dst[i]], 1);
}

// ---------- exclusive scan over cnt (3-phase) ----------
__global__ void scan1_kernel(const int* __restrict__ cnt, int NN, int* __restrict__ partials) {
    __shared__ int sh[256];
    int i = blockIdx.x * 256 + threadIdx.x;
    sh[threadIdx.x] = (i < NN) ? cnt[i] : 0;
    __syncthreads();
    for (int s = 128; s > 0; s >>= 1) {
        if (threadIdx.x < s) sh[threadIdx.x] += sh[threadIdx.x + s];
        __syncthreads();
    }
    if (threadIdx.x == 0) partials[blockIdx.x] = sh[0];
}

__global__ void scan2_kernel(const int* __restrict__ partials, int nb, int* __restrict__ pscan) {
    if (threadIdx.x == 0) {
        int run = 0;
        for (int b = 0; b < nb; ++b) { pscan[b] = run; run += partials[b]; }
    }
}

__global__ void scan3_kernel(const int* __restrict__ cnt, int NN, const int* __restrict__ pscan,
                             int* __restrict__ offs, int* __restrict__ cursor,
                             float* __restrict__ dinv) {
    __shared__ int sh[256];
    int t = threadIdx.x;
    int i = blockIdx.x * 256 + t;
    int v = (i < NN) ? cnt[i] : 0;
    sh[t] = v;
    __syncthreads();
    for (int d = 1; d < 256; d <<= 1) {
        int x = (t >= d) ? sh[t - d] : 0;
        __syncthreads();
        sh[t] += x;
        __syncthreads();
    }
    int incl = sh[t];
    int excl = incl - v;
    int base = pscan[blockIdx.x];
    if (i < NN) {
        offs[i]   = base + excl;
        cursor[i] = base + excl;
        dinv[i]   = rsqrtf((float)v + 1.0f);   // +1 self-loop; always >= 1
        if (i == NN - 1) offs[NN] = base + incl;
    }
}

// ---------- bucket edges by dst ----------
__global__ void scatter_kernel(const int* __restrict__ src, const int* __restrict__ dst, int E,
                               int* __restrict__ cursor, int* __restrict__ ssrc) {
    int i = blockIdx.x * blockDim.x + threadIdx.x;
    int stride = gridDim.x * blockDim.x;
    for (; i < E; i += stride) {
        int d = dst[i];
        int pos = atomicAdd(&cursor[d], 1);
        ssrc[pos] = src[i];
    }
}

// ---------- GEMM1: H1(bf16)[M,256] = X[M,256] @ W1[256,256], f32 accumulate ----------
// block 256 threads, tile M=64 x N=256, K staged in chunks of 32
__global__ __launch_bounds__(256) void gemm1_kernel(const float* __restrict__ X,
                                                    const float* __restrict__ W,
                                                    ushort* __restrict__ H1, int M) {
    __shared__ __align__(16) float As[32][68];   // [k][m], padded stride (68*4B, 16B-aligned rows)
    __shared__ __align__(16) float Bs[32][256];  // [k][n]
    int tid = threadIdx.x;
    int row0 = blockIdx.x * 64;
    int c0 = (tid & 63) * 4;        // output col base
    int rb = (tid >> 6) * 16;       // output row base within tile
    float acc[16][4];
    #pragma unroll
    for (int i = 0; i < 16; ++i)
        #pragma unroll
        for (int j = 0; j < 4; ++j) acc[i][j] = 0.f;

    int ar  = tid >> 3;          // 0..31
    int akq = (tid & 7) * 4;     // k sub-offset

    for (int k0 = 0; k0 < 256; k0 += 32) {
        // stage A (64x32), transposed into As[k][m]
        #pragma unroll
        for (int h = 0; h < 2; ++h) {
            int r = ar + h * 32;
            int grow = row0 + r;
            float4 v = make_float4(0.f, 0.f, 0.f, 0.f);
            if (grow < M) v = *reinterpret_cast<const float4*>(&X[(size_t)grow * 256 + k0 + akq]);
            As[akq + 0][r] = v.x;
            As[akq + 1][r] = v.y;
            As[akq + 2][r] = v.z;
            As[akq + 3][r] = v.w;
        }
        // stage B (32x256)
        #pragma unroll
        for (int h = 0; h < 8; ++h) {
            int f = tid + h * 256;
            int brr = f >> 6;
            int bcc = (f & 63) * 4;
            *reinterpret_cast<float4*>(&Bs[brr][bcc]) =
                *reinterpret_cast<const float4*>(&W[(size_t)(k0 + brr) * 256 + bcc]);
        }
        __syncthreads();
        #pragma unroll
        for (int kk = 0; kk < 32; ++kk) {
            float4 b  = *reinterpret_cast<const float4*>(&Bs[kk][c0]);
            float4 a0 = *reinterpret_cast<const float4*>(&As[kk][rb]);
            float4 a1 = *reinterpret_cast<const float4*>(&As[kk][rb + 4]);
            float4 a2 = *reinterpret_cast<const float4*>(&As[kk][rb + 8]);
            float4 a3 = *reinterpret_cast<const float4*>(&As[kk][rb + 12]);
            float a[16] = {a0.x, a0.y, a0.z, a0.w, a1.x, a1.y, a1.z, a1.w,
                           a2.x, a2.y, a2.z, a2.w, a3.x, a3.y, a3.z, a3.w};
            float bb[4] = {b.x, b.y, b.z, b.w};
            #pragma unroll
            for (int i = 0; i < 16; ++i)
                #pragma unroll
                for (int j = 0; j < 4; ++j)
                    acc[i][j] = fmaf(a[i], bb[j], acc[i][j]);
        }
        __syncthreads();
    }
    // epilogue: pack 4 f32 -> 4 bf16 (8B) per row
    #pragma unroll
    for (int i = 0; i < 16; ++i) {
        int grow = row0 + rb + i;
        if (grow < M) {
            uint lo = (uint)f2bf(acc[i][0]) | ((uint)f2bf(acc[i][1]) << 16);
            uint hi = (uint)f2bf(acc[i][2]) | ((uint)f2bf(acc[i][3]) << 16);
            *reinterpret_cast<uint2*>(&H1[(size_t)grow * 256 + c0]) = make_uint2(lo, hi);
        }
    }
}

// ---------- layer-1 aggregation (+b1, ELU) fused with GEMM2 (256->10) ----------
// one wave per node: 64 lanes x 4 features
__global__ __launch_bounds__(256) void agg1_gemm2_kernel(
    const ushort* __restrict__ H1, const int* __restrict__ offs, const int* __restrict__ ssrc,
    const float* __restrict__ dinv, const float* __restrict__ b1, const float* __restrict__ W2,
    float* __restrict__ H2, int NN) {
    int lane = threadIdx.x & 63;
    int node = blockIdx.x * 4 + (threadIdx.x >> 6);
    if (node >= NN) return;
    float dn = dinv[node];
    int beg = offs[node], end = offs[node + 1];
    int col = lane * 4;
    float acc0 = 0.f, acc1 = 0.f, acc2 = 0.f, acc3 = 0.f;
    #pragma unroll 4
    for (int i = beg; i < end; ++i) {
        int s = ssrc[i];
        float w = dinv[s];
        uint2 pv = *reinterpret_cast<const uint2*>(&H1[(size_t)s * 256 + col]);
        acc0 = fmaf(w, bf2f(pv.x & 0xffffu), acc0);
        acc1 = fmaf(w, bf2f(pv.x >> 16),     acc1);
        acc2 = fmaf(w, bf2f(pv.y & 0xffffu), acc2);
        acc3 = fmaf(w, bf2f(pv.y >> 16),     acc3);
    }
    {   // self loop: weight dinv[node]^2 = dn * (dn applied below)
        uint2 pv = *reinterpret_cast<const uint2*>(&H1[(size_t)node * 256 + col]);
        acc0 = fmaf(dn, bf2f(pv.x & 0xffffu), acc0);
        acc1 = fmaf(dn, bf2f(pv.x >> 16),     acc1);
        acc2 = fmaf(dn, bf2f(pv.y & 0xffffu), acc2);
        acc3 = fmaf(dn, bf2f(pv.y >> 16),     acc3);
    }
    float a0 = elu(fmaf(acc0, dn, b1[col + 0]));
    float a1 = elu(fmaf(acc1, dn, b1[col + 1]));
    float a2 = elu(fmaf(acc2, dn, b1[col + 2]));
    float a3 = elu(fmaf(acc3, dn, b1[col + 3]));
    // fused GEMM2: h2[node][c] = sum_k act1[node][k] * W2[k][c]
    float hv = 0.f;
    #pragma unroll
    for (int c = 0; c < 10; ++c) {
        float p = a0 * W2[(col + 0) * 10 + c]
                + a1 * W2[(col + 1) * 10 + c]
                + a2 * W2[(col + 2) * 10 + c]
                + a3 * W2[(col + 3) * 10 + c];
        #pragma unroll
        for (int m = 1; m < 64; m <<= 1) p += __shfl_xor(p, m, 64);
        if (lane == c) hv = p;
    }
    if (lane < 10) H2[(size_t)node * 10 + lane] = hv;
}

// ---------- layer-2 aggregation (+b2, ELU) fused with mean-pool accumulation ----------
// 16 threads per node (10 active feature lanes)
__global__ __launch_bounds__(256) void agg2_pool_kernel(
    const float* __restrict__ H2, const int* __restrict__ offs, const int* __restrict__ ssrc,
    const float* __restrict__ dinv, const float* __restrict__ b2, const int* __restrict__ batch,
    float* __restrict__ pool, float* __restrict__ pcnt, int NN) {
    int t = threadIdx.x;
    int node = blockIdx.x * 16 + (t >> 4);
    int c = t & 15;
    if (node >= NN) return;
    int g = batch[node];
    if (c == 0) atomicAdd(&pcnt[g], 1.0f);
    if (c >= 10) return;
    float dn = dinv[node];
    int beg = offs[node], end = offs[node + 1];
    float acc = 0.f;
    for (int i = beg; i < end; ++i) {
        int s = ssrc[i];
        acc = fmaf(dinv[s], H2[(size_t)s * 10 + c], acc);
    }
    acc = fmaf(dn, H2[(size_t)node * 10 + c], acc);   // self loop
    acc = fmaf(acc, dn, b2[c]);
    atomicAdd(&pool[g * 10 + c], elu(acc));
}

// ---------- mean + log_softmax ----------
__global__ void final_kernel(const float* __restrict__ pool, const float* __restrict__ pcnt,
                             float* __restrict__ out, int NG) {
    int g = threadIdx.x;
    if (g >= NG) return;
    float cn = fmaxf(pcnt[g], 1.0f);
    float m[10];
    float mx = -1e30f;
    #pragma unroll
    for (int c = 0; c < 10; ++c) {
        m[c] = pool[g * 10 + c] / cn;
        mx = fmaxf(mx, m[c]);
    }
    float s = 0.f;
    #pragma unroll
    for (int c = 0; c < 10; ++c) s += expf(m[c] - mx);
    float lse = logf(s) + mx;
    #pragma unroll
    for (int c = 0; c < 10; ++c) out[g * 10 + c] = m[c] - lse;
}

extern "C" void kernel_launch(void* const* d_in, const int* in_sizes, int n_in,
                              void* d_out, int out_size, void* d_ws, size_t ws_size,
                              hipStream_t stream) {
    const float* x     = (const float*)d_in[0];
    const int*   eidx  = (const int*)d_in[1];
    const int*   batch = (const int*)d_in[2];
    const float* W1    = (const float*)d_in[3];
    const float* b1    = (const float*)d_in[4];
    const float* W2    = (const float*)d_in[5];
    const float* b2    = (const float*)d_in[6];

    int NN = in_sizes[0] / 256;     // 50000
    int E  = in_sizes[1] / 2;       // 1600000
    int NG = out_size / 10;         // 64
    const int* src = eidx;
    const int* dst = eidx + E;

    char* ws = (char*)d_ws;
    size_t off = 0;
    auto alloc = [&](size_t bytes) -> void* {
        void* p = ws + off;
        off += (bytes + 255) & ~((size_t)255);
        return p;
    };
    int*    cnt      = (int*)alloc((size_t)NN * 4);
    int*    offs     = (int*)alloc((size_t)(NN + 1) * 4);
    int*    cursor   = (int*)alloc((size_t)NN * 4);
    int*    partials = (int*)alloc(256 * 4);
    int*    pscan    = (int*)alloc(256 * 4);
    float*  dinv     = (float*)alloc((size_t)NN * 4);
    int*    ssrc     = (int*)alloc((size_t)E * 4);
    ushort* H1       = (ushort*)alloc((size_t)NN * 256 * 2);
    float*  H2       = (float*)alloc((size_t)NN * 10 * 4);
    float*  pool     = (float*)alloc((size_t)NG * 10 * 4);
    float*  pcnt     = (float*)alloc((size_t)NG * 4);

    hipMemsetAsync(cnt,  0, (size_t)NN * 4,      stream);
    hipMemsetAsync(pool, 0, (size_t)NG * 10 * 4, stream);
    hipMemsetAsync(pcnt, 0, (size_t)NG * 4,      stream);

    int nb = (NN + 255) / 256;
    count_kernel  <<<1024, 256, 0, stream>>>(dst, E, cnt);
    scan1_kernel  <<<nb, 256, 0, stream>>>(cnt, NN, partials);
    scan2_kernel  <<<1, 64, 0, stream>>>(partials, nb, pscan);
    scan3_kernel  <<<nb, 256, 0, stream>>>(cnt, NN, pscan, offs, cursor, dinv);
    scatter_kernel<<<1024, 256, 0, stream>>>(src, dst, E, cursor, ssrc);
    gemm1_kernel  <<<(NN + 63) / 64, 256, 0, stream>>>(x, W1, H1, NN);
    agg1_gemm2_kernel<<<(NN + 3) / 4, 256, 0, stream>>>(H1, offs, ssrc, dinv, b1, W2, H2, NN);
    agg2_pool_kernel <<<(NN + 15) / 16, 256, 0, stream>>>(H2, offs, ssrc, dinv, b2, batch, pool, pcnt, NN);
    final_kernel  <<<1, 64, 0, stream>>>(pool, pcnt, (float*)d_out, NG);
}

// Round 2
// 489.895 us; speedup vs baseline: 1.7904x; 1.7904x over previous
//
#include <hip/hip_runtime.h>
#include <hip/hip_bf16.h>
#include <math.h>

typedef unsigned int uint;
typedef unsigned short ushort;

// ---------- small helpers ----------
__device__ __forceinline__ float bf2f(uint u) {
    return __uint_as_float(u << 16);
}
__device__ __forceinline__ ushort f2bf(float f) {
    uint u = __float_as_uint(f);
    uint rounding = 0x7fffu + ((u >> 16) & 1u);   // round-to-nearest-even
    return (ushort)((u + rounding) >> 16);
}
__device__ __forceinline__ float elu(float x) {
    return x > 0.f ? x : expm1f(x);
}

// ---------- degree histogram ----------
__global__ void count_kernel(const int* __restrict__ dst, int E, int* __restrict__ cnt) {
    int i = blockIdx.x * blockDim.x + threadIdx.x;
    int stride = gridDim.x * blockDim.x;
    for (; i < E; i += stride) atomicAdd(&cnt[dst[i]], 1);
}

// ---------- exclusive scan over cnt (3-phase) ----------
__global__ void scan1_kernel(const int* __restrict__ cnt, int NN, int* __restrict__ partials) {
    __shared__ int sh[256];
    int i = blockIdx.x * 256 + threadIdx.x;
    sh[threadIdx.x] = (i < NN) ? cnt[i] : 0;
    __syncthreads();
    for (int s = 128; s > 0; s >>= 1) {
        if (threadIdx.x < s) sh[threadIdx.x] += sh[threadIdx.x + s];
        __syncthreads();
    }
    if (threadIdx.x == 0) partials[blockIdx.x] = sh[0];
}

__global__ void scan2_kernel(const int* __restrict__ partials, int nb, int* __restrict__ pscan) {
    if (threadIdx.x == 0) {
        int run = 0;
        for (int b = 0; b < nb; ++b) { pscan[b] = run; run += partials[b]; }
    }
}

__global__ void scan3_kernel(const int* __restrict__ cnt, int NN, const int* __restrict__ pscan,
                             int* __restrict__ offs, int* __restrict__ cursor,
                             float* __restrict__ dinv) {
    __shared__ int sh[256];
    int t = threadIdx.x;
    int i = blockIdx.x * 256 + t;
    int v = (i < NN) ? cnt[i] : 0;
    sh[t] = v;
    __syncthreads();
    for (int d = 1; d < 256; d <<= 1) {
        int x = (t >= d) ? sh[t - d] : 0;
        __syncthreads();
        sh[t] += x;
        __syncthreads();
    }
    int incl = sh[t];
    int excl = incl - v;
    int base = pscan[blockIdx.x];
    if (i < NN) {
        offs[i]   = base + excl;
        cursor[i] = base + excl;
        dinv[i]   = rsqrtf((float)v + 1.0f);   // +1 self-loop; always >= 1
        if (i == NN - 1) offs[NN] = base + incl;
    }
}

// ---------- bucket edges by dst ----------
__global__ void scatter_kernel(const int* __restrict__ src, const int* __restrict__ dst, int E,
                               int* __restrict__ cursor, int* __restrict__ ssrc) {
    int i = blockIdx.x * blockDim.x + threadIdx.x;
    int stride = gridDim.x * blockDim.x;
    for (; i < E; i += stride) {
        int d = dst[i];
        int pos = atomicAdd(&cursor[d], 1);
        ssrc[pos] = src[i];
    }
}

// ---------- graph boundaries via binary search on sorted batch ----------
__global__ void gstart_kernel(const int* __restrict__ batch, int NN, int NG,
                              int* __restrict__ gstart) {
    int g = blockIdx.x * blockDim.x + threadIdx.x;
    if (g > NG) return;
    int lo = 0, hi = NN;
    while (lo < hi) {
        int mid = (lo + hi) >> 1;
        if (batch[mid] < g) lo = mid + 1; else hi = mid;
    }
    gstart[g] = lo;
}

// ---------- GEMM1: H1s(bf16)[M,256] = dinv[m] * (X[M,256] @ W1[256,256]) ----------
// block 256 threads, tile M=64 x N=256, K staged in chunks of 32
__global__ __launch_bounds__(256) void gemm1_kernel(const float* __restrict__ X,
                                                    const float* __restrict__ W,
                                                    const float* __restrict__ dinv,
                                                    ushort* __restrict__ H1, int M) {
    __shared__ __align__(16) float As[32][68];   // [k][m], padded stride
    __shared__ __align__(16) float Bs[32][256];  // [k][n]
    int tid = threadIdx.x;
    int row0 = blockIdx.x * 64;
    int c0 = (tid & 63) * 4;        // output col base
    int rb = (tid >> 6) * 16;       // output row base within tile
    float acc[16][4];
    #pragma unroll
    for (int i = 0; i < 16; ++i)
        #pragma unroll
        for (int j = 0; j < 4; ++j) acc[i][j] = 0.f;

    int ar  = tid >> 3;          // 0..31
    int akq = (tid & 7) * 4;     // k sub-offset

    for (int k0 = 0; k0 < 256; k0 += 32) {
        #pragma unroll
        for (int h = 0; h < 2; ++h) {
            int r = ar + h * 32;
            int grow = row0 + r;
            float4 v = make_float4(0.f, 0.f, 0.f, 0.f);
            if (grow < M) v = *reinterpret_cast<const float4*>(&X[(size_t)grow * 256 + k0 + akq]);
            As[akq + 0][r] = v.x;
            As[akq + 1][r] = v.y;
            As[akq + 2][r] = v.z;
            As[akq + 3][r] = v.w;
        }
        #pragma unroll
        for (int h = 0; h < 8; ++h) {
            int f = tid + h * 256;
            int brr = f >> 6;
            int bcc = (f & 63) * 4;
            *reinterpret_cast<float4*>(&Bs[brr][bcc]) =
                *reinterpret_cast<const float4*>(&W[(size_t)(k0 + brr) * 256 + bcc]);
        }
        __syncthreads();
        #pragma unroll
        for (int kk = 0; kk < 32; ++kk) {
            float4 b  = *reinterpret_cast<const float4*>(&Bs[kk][c0]);
            float4 a0 = *reinterpret_cast<const float4*>(&As[kk][rb]);
            float4 a1 = *reinterpret_cast<const float4*>(&As[kk][rb + 4]);
            float4 a2 = *reinterpret_cast<const float4*>(&As[kk][rb + 8]);
            float4 a3 = *reinterpret_cast<const float4*>(&As[kk][rb + 12]);
            float a[16] = {a0.x, a0.y, a0.z, a0.w, a1.x, a1.y, a1.z, a1.w,
                           a2.x, a2.y, a2.z, a2.w, a3.x, a3.y, a3.z, a3.w};
            float bb[4] = {b.x, b.y, b.z, b.w};
            #pragma unroll
            for (int i = 0; i < 16; ++i)
                #pragma unroll
                for (int j = 0; j < 4; ++j)
                    acc[i][j] = fmaf(a[i], bb[j], acc[i][j]);
        }
        __syncthreads();
    }
    // epilogue: scale by dinv[row], pack 4 f32 -> 4 bf16 (8B) per row
    #pragma unroll
    for (int i = 0; i < 16; ++i) {
        int grow = row0 + rb + i;
        if (grow < M) {
            float dn = dinv[grow];
            uint lo = (uint)f2bf(acc[i][0] * dn) | ((uint)f2bf(acc[i][1] * dn) << 16);
            uint hi = (uint)f2bf(acc[i][2] * dn) | ((uint)f2bf(acc[i][3] * dn) << 16);
            *reinterpret_cast<uint2*>(&H1[(size_t)grow * 256 + c0]) = make_uint2(lo, hi);
        }
    }
}

// ---------- layer-1 aggregation (+b1, ELU) fused with GEMM2 (256->10) ----------
// one wave per node: 64 lanes x 4 features; H1 is pre-scaled by dinv[src]
// writes H2s[node][c] = dinv[node] * (act1 @ W2)[c]
__global__ __launch_bounds__(256) void agg1_gemm2_kernel(
    const ushort* __restrict__ H1, const int* __restrict__ offs, const int* __restrict__ ssrc,
    const float* __restrict__ dinv, const float* __restrict__ b1, const float* __restrict__ W2,
    float* __restrict__ H2, int NN) {
    int lane = threadIdx.x & 63;
    int node = blockIdx.x * 4 + (threadIdx.x >> 6);
    if (node >= NN) return;
    int beg = offs[node], end = offs[node + 1];
    int col = lane * 4;
    const ushort* H1c = H1 + col;
    float acc0 = 0.f, acc1 = 0.f, acc2 = 0.f, acc3 = 0.f;
    int i = beg;
    for (; i + 3 < end; i += 4) {
        int s0 = ssrc[i], s1 = ssrc[i + 1], s2 = ssrc[i + 2], s3 = ssrc[i + 3];
        uint2 p0 = *reinterpret_cast<const uint2*>(H1c + (size_t)s0 * 256);
        uint2 p1 = *reinterpret_cast<const uint2*>(H1c + (size_t)s1 * 256);
        uint2 p2 = *reinterpret_cast<const uint2*>(H1c + (size_t)s2 * 256);
        uint2 p3 = *reinterpret_cast<const uint2*>(H1c + (size_t)s3 * 256);
        acc0 += bf2f(p0.x & 0xffffu) + bf2f(p1.x & 0xffffu) + bf2f(p2.x & 0xffffu) + bf2f(p3.x & 0xffffu);
        acc1 += bf2f(p0.x >> 16)     + bf2f(p1.x >> 16)     + bf2f(p2.x >> 16)     + bf2f(p3.x >> 16);
        acc2 += bf2f(p0.y & 0xffffu) + bf2f(p1.y & 0xffffu) + bf2f(p2.y & 0xffffu) + bf2f(p3.y & 0xffffu);
        acc3 += bf2f(p0.y >> 16)     + bf2f(p1.y >> 16)     + bf2f(p2.y >> 16)     + bf2f(p3.y >> 16);
    }
    for (; i < end; ++i) {
        int s = ssrc[i];
        uint2 p = *reinterpret_cast<const uint2*>(H1c + (size_t)s * 256);
        acc0 += bf2f(p.x & 0xffffu);
        acc1 += bf2f(p.x >> 16);
        acc2 += bf2f(p.y & 0xffffu);
        acc3 += bf2f(p.y >> 16);
    }
    {   // self loop: dinv[node]*h1[node] == H1s[node]
        uint2 p = *reinterpret_cast<const uint2*>(H1c + (size_t)node * 256);
        acc0 += bf2f(p.x & 0xffffu);
        acc1 += bf2f(p.x >> 16);
        acc2 += bf2f(p.y & 0xffffu);
        acc3 += bf2f(p.y >> 16);
    }
    float dn = dinv[node];
    float a0 = elu(fmaf(acc0, dn, b1[col + 0]));
    float a1 = elu(fmaf(acc1, dn, b1[col + 1]));
    float a2 = elu(fmaf(acc2, dn, b1[col + 2]));
    float a3 = elu(fmaf(acc3, dn, b1[col + 3]));
    // fused GEMM2: h2[node][c] = sum_k act1[node][k] * W2[k][c]
    float hv = 0.f;
    #pragma unroll
    for (int c = 0; c < 10; ++c) {
        float p = a0 * W2[(col + 0) * 10 + c]
                + a1 * W2[(col + 1) * 10 + c]
                + a2 * W2[(col + 2) * 10 + c]
                + a3 * W2[(col + 3) * 10 + c];
        #pragma unroll
        for (int m = 1; m < 64; m <<= 1) p += __shfl_xor(p, m, 64);
        if (lane == c) hv = p;
    }
    if (lane < 10) H2[(size_t)node * 10 + lane] = dn * hv;   // fold dinv[node] for layer 2
}

// ---------- layer-2 aggregation (+b2, ELU) -> per-node activations ----------
// 32 lanes per node: c = sub&15 (10 used), e2 = sub>>4 gives 2-way edge parallelism
__global__ __launch_bounds__(256) void agg2_elu_kernel(
    const float* __restrict__ H2, const int* __restrict__ offs, const int* __restrict__ ssrc,
    const float* __restrict__ dinv, const float* __restrict__ b2,
    float* __restrict__ H2act, int NN) {
    int t = threadIdx.x;
    int node = blockIdx.x * 8 + (t >> 5);
    if (node >= NN) return;
    int sub = t & 31;
    int c = sub & 15;
    int e2 = sub >> 4;
    int beg = offs[node], end = offs[node + 1];
    float acc = 0.f;
    int i = beg + e2;
    for (; i + 6 < end; i += 8) {   // this thread: i, i+2, i+4, i+6
        int s0 = ssrc[i], s1 = ssrc[i + 2], s2 = ssrc[i + 4], s3 = ssrc[i + 6];
        float h0 = H2[(size_t)s0 * 10 + c];
        float h1 = H2[(size_t)s1 * 10 + c];
        float h2 = H2[(size_t)s2 * 10 + c];
        float h3 = H2[(size_t)s3 * 10 + c];
        acc += (h0 + h1) + (h2 + h3);
    }
    for (; i < end; i += 2) acc += H2[(size_t)ssrc[i] * 10 + c];
    if (e2 == 0) acc += H2[(size_t)node * 10 + c];   // self loop (pre-scaled)
    acc += __shfl_xor(acc, 16, 64);                  // combine the two edge halves
    if (sub < 10) {
        float dn = dinv[node];
        H2act[(size_t)node * 10 + c] = elu(fmaf(dn, acc, b2[c]));
    }
}

// ---------- per-graph mean pool + log_softmax (no atomics) ----------
__global__ __launch_bounds__(320) void pool_final_kernel(
    const float* __restrict__ H2act, const int* __restrict__ gstart,
    float* __restrict__ out, int NG) {
    __shared__ float red[32][10];
    __shared__ float m[10];
    __shared__ float s_lse;
    int g = blockIdx.x;
    int t = threadIdx.x;
    int grp = t / 10;
    int c = t - grp * 10;
    int lo = gstart[g], hi = gstart[g + 1];
    float acc = 0.f;
    if (grp < 32) {
        for (int n = lo + grp; n < hi; n += 32) acc += H2act[(size_t)n * 10 + c];
        red[grp][c] = acc;
    }
    __syncthreads();
    if (t < 10) {
        float s = 0.f;
        #pragma unroll
        for (int j = 0; j < 32; ++j) s += red[j][t];
        m[t] = s / fmaxf((float)(hi - lo), 1.0f);
    }
    __syncthreads();
    if (t == 0) {
        float mx = -1e30f;
        for (int c2 = 0; c2 < 10; ++c2) mx = fmaxf(mx, m[c2]);
        float s = 0.f;
        for (int c2 = 0; c2 < 10; ++c2) s += expf(m[c2] - mx);
        s_lse = logf(s) + mx;
    }
    __syncthreads();
    if (t < 10) out[g * 10 + t] = m[t] - s_lse;
}

extern "C" void kernel_launch(void* const* d_in, const int* in_sizes, int n_in,
                              void* d_out, int out_size, void* d_ws, size_t ws_size,
                              hipStream_t stream) {
    const float* x     = (const float*)d_in[0];
    const int*   eidx  = (const int*)d_in[1];
    const int*   batch = (const int*)d_in[2];
    const float* W1    = (const float*)d_in[3];
    const float* b1    = (const float*)d_in[4];
    const float* W2    = (const float*)d_in[5];
    const float* b2    = (const float*)d_in[6];

    int NN = in_sizes[0] / 256;     // 50000
    int E  = in_sizes[1] / 2;       // 1600000
    int NG = out_size / 10;         // 64
    const int* src = eidx;
    const int* dst = eidx + E;

    char* ws = (char*)d_ws;
    size_t off = 0;
    auto alloc = [&](size_t bytes) -> void* {
        void* p = ws + off;
        off += (bytes + 255) & ~((size_t)255);
        return p;
    };
    int*    cnt      = (int*)alloc((size_t)NN * 4);
    int*    offs     = (int*)alloc((size_t)(NN + 1) * 4);
    int*    cursor   = (int*)alloc((size_t)NN * 4);
    int*    partials = (int*)alloc(256 * 4);
    int*    pscan    = (int*)alloc(256 * 4);
    float*  dinv     = (float*)alloc((size_t)NN * 4);
    int*    gstart   = (int*)alloc((size_t)(NG + 1) * 4);
    int*    ssrc     = (int*)alloc((size_t)E * 4);
    ushort* H1       = (ushort*)alloc((size_t)NN * 256 * 2);
    float*  H2       = (float*)alloc((size_t)NN * 10 * 4);
    float*  H2act    = (float*)alloc((size_t)NN * 10 * 4);

    hipMemsetAsync(cnt, 0, (size_t)NN * 4, stream);

    int nb = (NN + 255) / 256;
    count_kernel  <<<1024, 256, 0, stream>>>(dst, E, cnt);
    scan1_kernel  <<<nb, 256, 0, stream>>>(cnt, NN, partials);
    scan2_kernel  <<<1, 64, 0, stream>>>(partials, nb, pscan);
    scan3_kernel  <<<nb, 256, 0, stream>>>(cnt, NN, pscan, offs, cursor, dinv);
    scatter_kernel<<<1024, 256, 0, stream>>>(src, dst, E, cursor, ssrc);
    gstart_kernel <<<1, 128, 0, stream>>>(batch, NN, NG, gstart);
    gemm1_kernel  <<<(NN + 63) / 64, 256, 0, stream>>>(x, W1, dinv, H1, NN);
    agg1_gemm2_kernel<<<(NN + 3) / 4, 256, 0, stream>>>(H1, offs, ssrc, dinv, b1, W2, H2, NN);
    agg2_elu_kernel  <<<(NN + 7) / 8, 256, 0, stream>>>(H2, offs, ssrc, dinv, b2, H2act, NN);
    pool_final_kernel<<<NG, 320, 0, stream>>>(H2act, gstart, (float*)d_out, NG);
}

// Round 3
// 406.426 us; speedup vs baseline: 2.1580x; 1.2054x over previous
//
#include <hip/hip_runtime.h>
#include <hip/hip_bf16.h>
#include <math.h>

typedef unsigned int uint;
typedef unsigned short ushort;

typedef __attribute__((ext_vector_type(8))) short bf16x8;
typedef __attribute__((ext_vector_type(4))) float f32x4;

// ---------- small helpers ----------
__device__ __forceinline__ float bf2f(uint u) {
    return __uint_as_float(u << 16);
}
__device__ __forceinline__ ushort f2bf(float f) {
    uint u = __float_as_uint(f);
    uint rounding = 0x7fffu + ((u >> 16) & 1u);   // round-to-nearest-even
    return (ushort)((u + rounding) >> 16);
}
__device__ __forceinline__ float elu(float x) {
    return x > 0.f ? x : expm1f(x);
}

// ---------- degree histogram ----------
__global__ void count_kernel(const int* __restrict__ dst, int E, int* __restrict__ cnt) {
    int i = blockIdx.x * blockDim.x + threadIdx.x;
    int stride = gridDim.x * blockDim.x;
    for (; i < E; i += stride) atomicAdd(&cnt[dst[i]], 1);
}

// ---------- exclusive scan over cnt (3-phase) ----------
__global__ void scan1_kernel(const int* __restrict__ cnt, int NN, int* __restrict__ partials) {
    __shared__ int sh[256];
    int i = blockIdx.x * 256 + threadIdx.x;
    sh[threadIdx.x] = (i < NN) ? cnt[i] : 0;
    __syncthreads();
    for (int s = 128; s > 0; s >>= 1) {
        if (threadIdx.x < s) sh[threadIdx.x] += sh[threadIdx.x + s];
        __syncthreads();
    }
    if (threadIdx.x == 0) partials[blockIdx.x] = sh[0];
}

__global__ void scan2_kernel(const int* __restrict__ partials, int nb, int* __restrict__ pscan) {
    if (threadIdx.x == 0) {
        int run = 0;
        for (int b = 0; b < nb; ++b) { pscan[b] = run; run += partials[b]; }
    }
}

__global__ void scan3_kernel(const int* __restrict__ cnt, int NN, const int* __restrict__ pscan,
                             int* __restrict__ offs, int* __restrict__ cursor,
                             float* __restrict__ dinv) {
    __shared__ int sh[256];
    int t = threadIdx.x;
    int i = blockIdx.x * 256 + t;
    int v = (i < NN) ? cnt[i] : 0;
    sh[t] = v;
    __syncthreads();
    for (int d = 1; d < 256; d <<= 1) {
        int x = (t >= d) ? sh[t - d] : 0;
        __syncthreads();
        sh[t] += x;
        __syncthreads();
    }
    int incl = sh[t];
    int excl = incl - v;
    int base = pscan[blockIdx.x];
    if (i < NN) {
        offs[i]   = base + excl;
        cursor[i] = base + excl;
        dinv[i]   = rsqrtf((float)v + 1.0f);   // +1 self-loop; always >= 1
        if (i == NN - 1) offs[NN] = base + incl;
    }
}

// ---------- bucket edges by dst ----------
__global__ void scatter_kernel(const int* __restrict__ src, const int* __restrict__ dst, int E,
                               int* __restrict__ cursor, int* __restrict__ ssrc) {
    int i = blockIdx.x * blockDim.x + threadIdx.x;
    int stride = gridDim.x * blockDim.x;
    for (; i < E; i += stride) {
        int d = dst[i];
        int pos = atomicAdd(&cursor[d], 1);
        ssrc[pos] = src[i];
    }
}

// ---------- graph boundaries via binary search on sorted batch ----------
__global__ void gstart_kernel(const int* __restrict__ batch, int NN, int NG,
                              int* __restrict__ gstart) {
    int g = blockIdx.x * blockDim.x + threadIdx.x;
    if (g > NG) return;
    int lo = 0, hi = NN;
    while (lo < hi) {
        int mid = (lo + hi) >> 1;
        if (batch[mid] < g) lo = mid + 1; else hi = mid;
    }
    gstart[g] = lo;
}

// ---------- W1T(bf16)[n][k] = W1[k][n], 64x64 tiles via LDS ----------
__global__ __launch_bounds__(256) void wtrans_kernel(const float* __restrict__ W,
                                                     ushort* __restrict__ WT) {
    __shared__ float T[64][68];
    int b = blockIdx.x;                 // 0..15
    int kt = (b >> 2) * 64, nt = (b & 3) * 64;
    int t = threadIdx.x;
    int r = t >> 4, c4 = (t & 15) * 4;
    #pragma unroll
    for (int h = 0; h < 4; ++h) {
        int rr = r + h * 16;
        float4 v = *reinterpret_cast<const float4*>(&W[(size_t)(kt + rr) * 256 + nt + c4]);
        *reinterpret_cast<float4*>(&T[rr][c4]) = v;
    }
    __syncthreads();
    int nr = t >> 2, ks = (t & 3) * 16;
    uint o[8];
    #pragma unroll
    for (int i = 0; i < 16; i += 2) {
        float f0 = T[ks + i][nr];
        float f1 = T[ks + i + 1][nr];
        o[i >> 1] = (uint)f2bf(f0) | ((uint)f2bf(f1) << 16);
    }
    size_t base = (size_t)(nt + nr) * 256 + kt + ks;
    *reinterpret_cast<uint4*>(&WT[base])     = make_uint4(o[0], o[1], o[2], o[3]);
    *reinterpret_cast<uint4*>(&WT[base + 8]) = make_uint4(o[4], o[5], o[6], o[7]);
}

// ---------- GEMM1 via MFMA: H1s(bf16)[M,256] = dinv[m] * (X @ W1) ----------
// block = 256 threads (4 waves), tile M=64 x N=256 (full), BK=32.
// Swapped operands: mfma(A=W-frag, B=X-frag) so each lane holds 4 consecutive
// n for one m-row -> packed 8B bf16 stores, no epilogue LDS.
#define G1_STRIDE 40   // ushorts per LDS row (80B = 20 banks; 16B-aligned frag reads)
__global__ __launch_bounds__(256) void gemm1_mfma_kernel(const float* __restrict__ X,
                                                         const ushort* __restrict__ W1T,
                                                         const float* __restrict__ dinv,
                                                         ushort* __restrict__ H1, int M) {
    __shared__ ushort Xs[64 * G1_STRIDE];
    __shared__ ushort Ws[256 * G1_STRIDE];
    __shared__ float  Dvs[64];
    int t = threadIdx.x;
    int row0 = blockIdx.x * 64;
    int lane = t & 63;
    int w = t >> 6;
    int lr = lane & 15;     // row/col within fragment
    int lg = lane >> 4;     // k-group (8 contiguous k per lane)

    if (t < 64) {
        int grow = row0 + t;
        Dvs[t] = (grow < M) ? dinv[grow] : 0.f;
    }

    f32x4 acc[4][4];
    #pragma unroll
    for (int j = 0; j < 4; ++j)
        #pragma unroll
        for (int i = 0; i < 4; ++i)
            acc[j][i] = (f32x4){0.f, 0.f, 0.f, 0.f};

    for (int k0 = 0; k0 < 256; k0 += 32) {
        // stage X tile (64 rows x 32 k), f32 -> bf16
        #pragma unroll
        for (int h = 0; h < 2; ++h) {
            int u = t + h * 256;
            int row = u >> 3;
            int kq = (u & 7) * 4;
            int grow = row0 + row;
            float4 v = make_float4(0.f, 0.f, 0.f, 0.f);
            if (grow < M) v = *reinterpret_cast<const float4*>(&X[(size_t)grow * 256 + k0 + kq]);
            uint lo = (uint)f2bf(v.x) | ((uint)f2bf(v.y) << 16);
            uint hi = (uint)f2bf(v.z) | ((uint)f2bf(v.w) << 16);
            *reinterpret_cast<uint2*>(&Xs[row * G1_STRIDE + kq]) = make_uint2(lo, hi);
        }
        // stage W tile (256 n x 32 k), already bf16
        #pragma unroll
        for (int h = 0; h < 4; ++h) {
            int u = t + h * 256;
            int n = u >> 2;
            int seg = u & 3;
            uint4 wv = *reinterpret_cast<const uint4*>(&W1T[(size_t)n * 256 + k0 + seg * 8]);
            *reinterpret_cast<uint4*>(&Ws[n * G1_STRIDE + seg * 8]) = wv;
        }
        __syncthreads();
        bf16x8 wf[4], xf[4];
        #pragma unroll
        for (int j = 0; j < 4; ++j)
            wf[j] = *reinterpret_cast<const bf16x8*>(&Ws[(w * 64 + j * 16 + lr) * G1_STRIDE + lg * 8]);
        #pragma unroll
        for (int i = 0; i < 4; ++i)
            xf[i] = *reinterpret_cast<const bf16x8*>(&Xs[(i * 16 + lr) * G1_STRIDE + lg * 8]);
        #pragma unroll
        for (int j = 0; j < 4; ++j)
            #pragma unroll
            for (int i = 0; i < 4; ++i)
                acc[j][i] = __builtin_amdgcn_mfma_f32_16x16x32_bf16(wf[j], xf[i], acc[j][i], 0, 0, 0);
        __syncthreads();
    }

    // epilogue: lane holds H1[row0 + mi*16 + lr][w*64 + nj*16 + lg*4 + r], r=0..3
    #pragma unroll
    for (int mi = 0; mi < 4; ++mi) {
        int grow = row0 + mi * 16 + lr;
        float dv = Dvs[mi * 16 + lr];
        bool ok = grow < M;
        #pragma unroll
        for (int nj = 0; nj < 4; ++nj) {
            f32x4 a = acc[nj][mi];
            uint lo = (uint)f2bf(a[0] * dv) | ((uint)f2bf(a[1] * dv) << 16);
            uint hi = (uint)f2bf(a[2] * dv) | ((uint)f2bf(a[3] * dv) << 16);
            if (ok) {
                int col = w * 64 + nj * 16 + lg * 4;
                *reinterpret_cast<uint2*>(&H1[(size_t)grow * 256 + col]) = make_uint2(lo, hi);
            }
        }
    }
}

// ---------- layer-1 aggregation (+b1, ELU) fused with GEMM2 (256->10) ----------
// one wave per node: 64 lanes x 4 features; H1 is pre-scaled by dinv[src]
// writes H2s[node][c] = dinv[node] * (act1 @ W2)[c]
__global__ __launch_bounds__(256) void agg1_gemm2_kernel(
    const ushort* __restrict__ H1, const int* __restrict__ offs, const int* __restrict__ ssrc,
    const float* __restrict__ dinv, const float* __restrict__ b1, const float* __restrict__ W2,
    float* __restrict__ H2, int NN) {
    int lane = threadIdx.x & 63;
    int node = blockIdx.x * 4 + (threadIdx.x >> 6);
    if (node >= NN) return;
    int beg = offs[node], end = offs[node + 1];
    int col = lane * 4;
    const ushort* H1c = H1 + col;
    float acc0 = 0.f, acc1 = 0.f, acc2 = 0.f, acc3 = 0.f;
    int i = beg;
    for (; i + 3 < end; i += 4) {
        int s0 = ssrc[i], s1 = ssrc[i + 1], s2 = ssrc[i + 2], s3 = ssrc[i + 3];
        uint2 p0 = *reinterpret_cast<const uint2*>(H1c + (size_t)s0 * 256);
        uint2 p1 = *reinterpret_cast<const uint2*>(H1c + (size_t)s1 * 256);
        uint2 p2 = *reinterpret_cast<const uint2*>(H1c + (size_t)s2 * 256);
        uint2 p3 = *reinterpret_cast<const uint2*>(H1c + (size_t)s3 * 256);
        acc0 += bf2f(p0.x & 0xffffu) + bf2f(p1.x & 0xffffu) + bf2f(p2.x & 0xffffu) + bf2f(p3.x & 0xffffu);
        acc1 += bf2f(p0.x >> 16)     + bf2f(p1.x >> 16)     + bf2f(p2.x >> 16)     + bf2f(p3.x >> 16);
        acc2 += bf2f(p0.y & 0xffffu) + bf2f(p1.y & 0xffffu) + bf2f(p2.y & 0xffffu) + bf2f(p3.y & 0xffffu);
        acc3 += bf2f(p0.y >> 16)     + bf2f(p1.y >> 16)     + bf2f(p2.y >> 16)     + bf2f(p3.y >> 16);
    }
    for (; i < end; ++i) {
        int s = ssrc[i];
        uint2 p = *reinterpret_cast<const uint2*>(H1c + (size_t)s * 256);
        acc0 += bf2f(p.x & 0xffffu);
        acc1 += bf2f(p.x >> 16);
        acc2 += bf2f(p.y & 0xffffu);
        acc3 += bf2f(p.y >> 16);
    }
    {   // self loop: dinv[node]*h1[node] == H1s[node]
        uint2 p = *reinterpret_cast<const uint2*>(H1c + (size_t)node * 256);
        acc0 += bf2f(p.x & 0xffffu);
        acc1 += bf2f(p.x >> 16);
        acc2 += bf2f(p.y & 0xffffu);
        acc3 += bf2f(p.y >> 16);
    }
    float dn = dinv[node];
    float a0 = elu(fmaf(acc0, dn, b1[col + 0]));
    float a1 = elu(fmaf(acc1, dn, b1[col + 1]));
    float a2 = elu(fmaf(acc2, dn, b1[col + 2]));
    float a3 = elu(fmaf(acc3, dn, b1[col + 3]));
    // fused GEMM2: h2[node][c] = sum_k act1[node][k] * W2[k][c]
    float hv = 0.f;
    #pragma unroll
    for (int c = 0; c < 10; ++c) {
        float p = a0 * W2[(col + 0) * 10 + c]
                + a1 * W2[(col + 1) * 10 + c]
                + a2 * W2[(col + 2) * 10 + c]
                + a3 * W2[(col + 3) * 10 + c];
        #pragma unroll
        for (int m = 1; m < 64; m <<= 1) p += __shfl_xor(p, m, 64);
        if (lane == c) hv = p;
    }
    if (lane < 10) H2[(size_t)node * 10 + lane] = dn * hv;   // fold dinv[node] for layer 2
}

// ---------- layer-2 aggregation (+b2, ELU) -> per-node activations ----------
__global__ __launch_bounds__(256) void agg2_elu_kernel(
    const float* __restrict__ H2, const int* __restrict__ offs, const int* __restrict__ ssrc,
    const float* __restrict__ dinv, const float* __restrict__ b2,
    float* __restrict__ H2act, int NN) {
    int t = threadIdx.x;
    int node = blockIdx.x * 8 + (t >> 5);
    if (node >= NN) return;
    int sub = t & 31;
    int c = sub & 15;
    int e2 = sub >> 4;
    int beg = offs[node], end = offs[node + 1];
    float acc = 0.f;
    int i = beg + e2;
    for (; i + 6 < end; i += 8) {
        int s0 = ssrc[i], s1 = ssrc[i + 2], s2 = ssrc[i + 4], s3 = ssrc[i + 6];
        float h0 = H2[(size_t)s0 * 10 + c];
        float h1 = H2[(size_t)s1 * 10 + c];
        float h2 = H2[(size_t)s2 * 10 + c];
        float h3 = H2[(size_t)s3 * 10 + c];
        acc += (h0 + h1) + (h2 + h3);
    }
    for (; i < end; i += 2) acc += H2[(size_t)ssrc[i] * 10 + c];
    if (e2 == 0) acc += H2[(size_t)node * 10 + c];   // self loop (pre-scaled)
    acc += __shfl_xor(acc, 16, 64);                  // combine the two edge halves
    if (sub < 10) {
        float dn = dinv[node];
        H2act[(size_t)node * 10 + c] = elu(fmaf(dn, acc, b2[c]));
    }
}

// ---------- per-graph mean pool + log_softmax (no atomics) ----------
__global__ __launch_bounds__(320) void pool_final_kernel(
    const float* __restrict__ H2act, const int* __restrict__ gstart,
    float* __restrict__ out, int NG) {
    __shared__ float red[32][10];
    __shared__ float m[10];
    __shared__ float s_lse;
    int g = blockIdx.x;
    int t = threadIdx.x;
    int grp = t / 10;
    int c = t - grp * 10;
    int lo = gstart[g], hi = gstart[g + 1];
    float acc = 0.f;
    if (grp < 32) {
        for (int n = lo + grp; n < hi; n += 32) acc += H2act[(size_t)n * 10 + c];
        red[grp][c] = acc;
    }
    __syncthreads();
    if (t < 10) {
        float s = 0.f;
        #pragma unroll
        for (int j = 0; j < 32; ++j) s += red[j][t];
        m[t] = s / fmaxf((float)(hi - lo), 1.0f);
    }
    __syncthreads();
    if (t == 0) {
        float mx = -1e30f;
        for (int c2 = 0; c2 < 10; ++c2) mx = fmaxf(mx, m[c2]);
        float s = 0.f;
        for (int c2 = 0; c2 < 10; ++c2) s += expf(m[c2] - mx);
        s_lse = logf(s) + mx;
    }
    __syncthreads();
    if (t < 10) out[g * 10 + t] = m[t] - s_lse;
}

extern "C" void kernel_launch(void* const* d_in, const int* in_sizes, int n_in,
                              void* d_out, int out_size, void* d_ws, size_t ws_size,
                              hipStream_t stream) {
    const float* x     = (const float*)d_in[0];
    const int*   eidx  = (const int*)d_in[1];
    const int*   batch = (const int*)d_in[2];
    const float* W1    = (const float*)d_in[3];
    const float* b1    = (const float*)d_in[4];
    const float* W2    = (const float*)d_in[5];
    const float* b2    = (const float*)d_in[6];

    int NN = in_sizes[0] / 256;     // 50000
    int E  = in_sizes[1] / 2;       // 1600000
    int NG = out_size / 10;         // 64
    const int* src = eidx;
    const int* dst = eidx + E;

    char* ws = (char*)d_ws;
    size_t off = 0;
    auto alloc = [&](size_t bytes) -> void* {
        void* p = ws + off;
        off += (bytes + 255) & ~((size_t)255);
        return p;
    };
    int*    cnt      = (int*)alloc((size_t)NN * 4);
    int*    offs     = (int*)alloc((size_t)(NN + 1) * 4);
    int*    cursor   = (int*)alloc((size_t)NN * 4);
    int*    partials = (int*)alloc(256 * 4);
    int*    pscan    = (int*)alloc(256 * 4);
    float*  dinv     = (float*)alloc((size_t)NN * 4);
    int*    gstart   = (int*)alloc((size_t)(NG + 1) * 4);
    ushort* W1T      = (ushort*)alloc((size_t)256 * 256 * 2);
    int*    ssrc     = (int*)alloc((size_t)E * 4);
    ushort* H1       = (ushort*)alloc((size_t)NN * 256 * 2);
    float*  H2       = (float*)alloc((size_t)NN * 10 * 4);
    float*  H2act    = (float*)alloc((size_t)NN * 10 * 4);

    hipMemsetAsync(cnt, 0, (size_t)NN * 4, stream);

    int nb = (NN + 255) / 256;
    count_kernel  <<<1024, 256, 0, stream>>>(dst, E, cnt);
    scan1_kernel  <<<nb, 256, 0, stream>>>(cnt, NN, partials);
    scan2_kernel  <<<1, 64, 0, stream>>>(partials, nb, pscan);
    scan3_kernel  <<<nb, 256, 0, stream>>>(cnt, NN, pscan, offs, cursor, dinv);
    scatter_kernel<<<1024, 256, 0, stream>>>(src, dst, E, cursor, ssrc);
    gstart_kernel <<<1, 128, 0, stream>>>(batch, NN, NG, gstart);
    wtrans_kernel <<<16, 256, 0, stream>>>(W1, W1T);
    gemm1_mfma_kernel<<<(NN + 63) / 64, 256, 0, stream>>>(x, W1T, dinv, H1, NN);
    agg1_gemm2_kernel<<<(NN + 3) / 4, 256, 0, stream>>>(H1, offs, ssrc, dinv, b1, W2, H2, NN);
    agg2_elu_kernel  <<<(NN + 7) / 8, 256, 0, stream>>>(H2, offs, ssrc, dinv, b2, H2act, NN);
    pool_final_kernel<<<NG, 320, 0, stream>>>(H2act, gstart, (float*)d_out, NG);
}

// Round 4
// 352.570 us; speedup vs baseline: 2.4877x; 1.1528x over previous
//
#include <hip/hip_runtime.h>
#include <hip/hip_bf16.h>
#include <math.h>

typedef unsigned int uint;
typedef unsigned short ushort;

typedef __attribute__((ext_vector_type(8))) short bf16x8;
typedef __attribute__((ext_vector_type(4))) float f32x4;

// ---------- small helpers ----------
__device__ __forceinline__ float bf2f(uint u) {
    return __uint_as_float(u << 16);
}
__device__ __forceinline__ ushort f2bf(float f) {
    uint u = __float_as_uint(f);
    uint rounding = 0x7fffu + ((u >> 16) & 1u);   // round-to-nearest-even
    return (ushort)((u + rounding) >> 16);
}
__device__ __forceinline__ float elu(float x) {
    return x > 0.f ? x : expm1f(x);
}

// ---------- degree histogram ----------
__global__ void count_kernel(const int* __restrict__ dst, int E, int* __restrict__ cnt) {
    int i = blockIdx.x * blockDim.x + threadIdx.x;
    int stride = gridDim.x * blockDim.x;
    for (; i < E; i += stride) atomicAdd(&cnt[dst[i]], 1);
}

// ---------- exclusive scan over cnt (3-phase) ----------
__global__ void scan1_kernel(const int* __restrict__ cnt, int NN, int* __restrict__ partials) {
    __shared__ int sh[256];
    int i = blockIdx.x * 256 + threadIdx.x;
    sh[threadIdx.x] = (i < NN) ? cnt[i] : 0;
    __syncthreads();
    for (int s = 128; s > 0; s >>= 1) {
        if (threadIdx.x < s) sh[threadIdx.x] += sh[threadIdx.x + s];
        __syncthreads();
    }
    if (threadIdx.x == 0) partials[blockIdx.x] = sh[0];
}

__global__ void scan2_kernel(const int* __restrict__ partials, int nb, int* __restrict__ pscan) {
    if (threadIdx.x == 0) {
        int run = 0;
        for (int b = 0; b < nb; ++b) { pscan[b] = run; run += partials[b]; }
    }
}

__global__ void scan3_kernel(const int* __restrict__ cnt, int NN, const int* __restrict__ pscan,
                             int* __restrict__ offs, int* __restrict__ cursor,
                             float* __restrict__ dinv) {
    __shared__ int sh[256];
    int t = threadIdx.x;
    int i = blockIdx.x * 256 + t;
    int v = (i < NN) ? cnt[i] : 0;
    sh[t] = v;
    __syncthreads();
    for (int d = 1; d < 256; d <<= 1) {
        int x = (t >= d) ? sh[t - d] : 0;
        __syncthreads();
        sh[t] += x;
        __syncthreads();
    }
    int incl = sh[t];
    int excl = incl - v;
    int base = pscan[blockIdx.x];
    if (i < NN) {
        offs[i]   = base + excl;
        cursor[i] = base + excl;
        dinv[i]   = rsqrtf((float)v + 1.0f);   // +1 self-loop; always >= 1
        if (i == NN - 1) offs[NN] = base + incl;
    }
}

// ---------- bucket edges by dst, XCD-partitioned ----------
// group g = blockIdx&7 handles dst in [g*per, (g+1)*per): with round-robin
// block->XCD dispatch each XCD writes only its own ~800KB slice of ssrc and
// cursor -> slices stay L2-resident, no 16x HBM write amplification.
__global__ __launch_bounds__(256) void scatter_kernel(const int* __restrict__ src,
                                                      const int* __restrict__ dst, int E,
                                                      int* __restrict__ cursor,
                                                      int* __restrict__ ssrc, int NN) {
    int grp = blockIdx.x & 7;
    int per = (NN + 7) >> 3;
    int lo = grp * per;
    int hi = min(NN, lo + per);
    int bid = blockIdx.x >> 3;
    int nb  = gridDim.x >> 3;
    int i = bid * blockDim.x + threadIdx.x;
    int stride = nb * blockDim.x;
    for (; i < E; i += stride) {
        int d = dst[i];
        if (d >= lo && d < hi) {
            int pos = atomicAdd(&cursor[d], 1);
            ssrc[pos] = src[i];
        }
    }
}

// ---------- graph boundaries via binary search on sorted batch ----------
__global__ void gstart_kernel(const int* __restrict__ batch, int NN, int NG,
                              int* __restrict__ gstart) {
    int g = blockIdx.x * blockDim.x + threadIdx.x;
    if (g > NG) return;
    int lo = 0, hi = NN;
    while (lo < hi) {
        int mid = (lo + hi) >> 1;
        if (batch[mid] < g) lo = mid + 1; else hi = mid;
    }
    gstart[g] = lo;
}

// ---------- W1T(bf16)[n][k] = W1[k][n], 64x64 tiles via LDS ----------
__global__ __launch_bounds__(256) void wtrans_kernel(const float* __restrict__ W,
                                                     ushort* __restrict__ WT) {
    __shared__ float T[64][68];
    int b = blockIdx.x;                 // 0..15
    int kt = (b >> 2) * 64, nt = (b & 3) * 64;
    int t = threadIdx.x;
    int r = t >> 4, c4 = (t & 15) * 4;
    #pragma unroll
    for (int h = 0; h < 4; ++h) {
        int rr = r + h * 16;
        float4 v = *reinterpret_cast<const float4*>(&W[(size_t)(kt + rr) * 256 + nt + c4]);
        *reinterpret_cast<float4*>(&T[rr][c4]) = v;
    }
    __syncthreads();
    int nr = t >> 2, ks = (t & 3) * 16;
    uint o[8];
    #pragma unroll
    for (int i = 0; i < 16; i += 2) {
        float f0 = T[ks + i][nr];
        float f1 = T[ks + i + 1][nr];
        o[i >> 1] = (uint)f2bf(f0) | ((uint)f2bf(f1) << 16);
    }
    size_t base = (size_t)(nt + nr) * 256 + kt + ks;
    *reinterpret_cast<uint4*>(&WT[base])     = make_uint4(o[0], o[1], o[2], o[3]);
    *reinterpret_cast<uint4*>(&WT[base + 8]) = make_uint4(o[4], o[5], o[6], o[7]);
}

// ---------- GEMM1 via MFMA: H1s(bf16)[M,256] = dinv[m] * (X @ W1) ----------
#define G1_STRIDE 40   // ushorts per LDS row (80B = 20 banks; 16B-aligned frag reads)
__global__ __launch_bounds__(256) void gemm1_mfma_kernel(const float* __restrict__ X,
                                                         const ushort* __restrict__ W1T,
                                                         const float* __restrict__ dinv,
                                                         ushort* __restrict__ H1, int M) {
    __shared__ ushort Xs[64 * G1_STRIDE];
    __shared__ ushort Ws[256 * G1_STRIDE];
    __shared__ float  Dvs[64];
    int t = threadIdx.x;
    int row0 = blockIdx.x * 64;
    int lane = t & 63;
    int w = t >> 6;
    int lr = lane & 15;     // row/col within fragment
    int lg = lane >> 4;     // k-group (8 contiguous k per lane)

    if (t < 64) {
        int grow = row0 + t;
        Dvs[t] = (grow < M) ? dinv[grow] : 0.f;
    }

    f32x4 acc[4][4];
    #pragma unroll
    for (int j = 0; j < 4; ++j)
        #pragma unroll
        for (int i = 0; i < 4; ++i)
            acc[j][i] = (f32x4){0.f, 0.f, 0.f, 0.f};

    for (int k0 = 0; k0 < 256; k0 += 32) {
        #pragma unroll
        for (int h = 0; h < 2; ++h) {
            int u = t + h * 256;
            int row = u >> 3;
            int kq = (u & 7) * 4;
            int grow = row0 + row;
            float4 v = make_float4(0.f, 0.f, 0.f, 0.f);
            if (grow < M) v = *reinterpret_cast<const float4*>(&X[(size_t)grow * 256 + k0 + kq]);
            uint lo = (uint)f2bf(v.x) | ((uint)f2bf(v.y) << 16);
            uint hi = (uint)f2bf(v.z) | ((uint)f2bf(v.w) << 16);
            *reinterpret_cast<uint2*>(&Xs[row * G1_STRIDE + kq]) = make_uint2(lo, hi);
        }
        #pragma unroll
        for (int h = 0; h < 4; ++h) {
            int u = t + h * 256;
            int n = u >> 2;
            int seg = u & 3;
            uint4 wv = *reinterpret_cast<const uint4*>(&W1T[(size_t)n * 256 + k0 + seg * 8]);
            *reinterpret_cast<uint4*>(&Ws[n * G1_STRIDE + seg * 8]) = wv;
        }
        __syncthreads();
        bf16x8 wf[4], xf[4];
        #pragma unroll
        for (int j = 0; j < 4; ++j)
            wf[j] = *reinterpret_cast<const bf16x8*>(&Ws[(w * 64 + j * 16 + lr) * G1_STRIDE + lg * 8]);
        #pragma unroll
        for (int i = 0; i < 4; ++i)
            xf[i] = *reinterpret_cast<const bf16x8*>(&Xs[(i * 16 + lr) * G1_STRIDE + lg * 8]);
        #pragma unroll
        for (int j = 0; j < 4; ++j)
            #pragma unroll
            for (int i = 0; i < 4; ++i)
                acc[j][i] = __builtin_amdgcn_mfma_f32_16x16x32_bf16(wf[j], xf[i], acc[j][i], 0, 0, 0);
        __syncthreads();
    }

    #pragma unroll
    for (int mi = 0; mi < 4; ++mi) {
        int grow = row0 + mi * 16 + lr;
        float dv = Dvs[mi * 16 + lr];
        bool ok = grow < M;
        #pragma unroll
        for (int nj = 0; nj < 4; ++nj) {
            f32x4 a = acc[nj][mi];
            uint lo = (uint)f2bf(a[0] * dv) | ((uint)f2bf(a[1] * dv) << 16);
            uint hi = (uint)f2bf(a[2] * dv) | ((uint)f2bf(a[3] * dv) << 16);
            if (ok) {
                int col = w * 64 + nj * 16 + lg * 4;
                *reinterpret_cast<uint2*>(&H1[(size_t)grow * 256 + col]) = make_uint2(lo, hi);
            }
        }
    }
}

// ---------- layer-1 aggregation (+b1, ELU) fused with GEMM2 (256->10) ----------
__global__ __launch_bounds__(256) void agg1_gemm2_kernel(
    const ushort* __restrict__ H1, const int* __restrict__ offs, const int* __restrict__ ssrc,
    const float* __restrict__ dinv, const float* __restrict__ b1, const float* __restrict__ W2,
    float* __restrict__ H2, int NN) {
    int lane = threadIdx.x & 63;
    int node = blockIdx.x * 4 + (threadIdx.x >> 6);
    if (node >= NN) return;
    int beg = offs[node], end = offs[node + 1];
    int col = lane * 4;
    const ushort* H1c = H1 + col;
    float acc0 = 0.f, acc1 = 0.f, acc2 = 0.f, acc3 = 0.f;
    int i = beg;
    for (; i + 3 < end; i += 4) {
        int s0 = ssrc[i], s1 = ssrc[i + 1], s2 = ssrc[i + 2], s3 = ssrc[i + 3];
        uint2 p0 = *reinterpret_cast<const uint2*>(H1c + (size_t)s0 * 256);
        uint2 p1 = *reinterpret_cast<const uint2*>(H1c + (size_t)s1 * 256);
        uint2 p2 = *reinterpret_cast<const uint2*>(H1c + (size_t)s2 * 256);
        uint2 p3 = *reinterpret_cast<const uint2*>(H1c + (size_t)s3 * 256);
        acc0 += bf2f(p0.x & 0xffffu) + bf2f(p1.x & 0xffffu) + bf2f(p2.x & 0xffffu) + bf2f(p3.x & 0xffffu);
        acc1 += bf2f(p0.x >> 16)     + bf2f(p1.x >> 16)     + bf2f(p2.x >> 16)     + bf2f(p3.x >> 16);
        acc2 += bf2f(p0.y & 0xffffu) + bf2f(p1.y & 0xffffu) + bf2f(p2.y & 0xffffu) + bf2f(p3.y & 0xffffu);
        acc3 += bf2f(p0.y >> 16)     + bf2f(p1.y >> 16)     + bf2f(p2.y >> 16)     + bf2f(p3.y >> 16);
    }
    for (; i < end; ++i) {
        int s = ssrc[i];
        uint2 p = *reinterpret_cast<const uint2*>(H1c + (size_t)s * 256);
        acc0 += bf2f(p.x & 0xffffu);
        acc1 += bf2f(p.x >> 16);
        acc2 += bf2f(p.y & 0xffffu);
        acc3 += bf2f(p.y >> 16);
    }
    {   // self loop
        uint2 p = *reinterpret_cast<const uint2*>(H1c + (size_t)node * 256);
        acc0 += bf2f(p.x & 0xffffu);
        acc1 += bf2f(p.x >> 16);
        acc2 += bf2f(p.y & 0xffffu);
        acc3 += bf2f(p.y >> 16);
    }
    float dn = dinv[node];
    float a0 = elu(fmaf(acc0, dn, b1[col + 0]));
    float a1 = elu(fmaf(acc1, dn, b1[col + 1]));
    float a2 = elu(fmaf(acc2, dn, b1[col + 2]));
    float a3 = elu(fmaf(acc3, dn, b1[col + 3]));
    float hv = 0.f;
    #pragma unroll
    for (int c = 0; c < 10; ++c) {
        float p = a0 * W2[(col + 0) * 10 + c]
                + a1 * W2[(col + 1) * 10 + c]
                + a2 * W2[(col + 2) * 10 + c]
                + a3 * W2[(col + 3) * 10 + c];
        #pragma unroll
        for (int m = 1; m < 64; m <<= 1) p += __shfl_xor(p, m, 64);
        if (lane == c) hv = p;
    }
    if (lane < 10) H2[(size_t)node * 10 + lane] = dn * hv;   // fold dinv[node] for layer 2
}

// ---------- layer-2 aggregation (+b2, ELU) -> per-node activations ----------
__global__ __launch_bounds__(256) void agg2_elu_kernel(
    const float* __restrict__ H2, const int* __restrict__ offs, const int* __restrict__ ssrc,
    const float* __restrict__ dinv, const float* __restrict__ b2,
    float* __restrict__ H2act, int NN) {
    int t = threadIdx.x;
    int node = blockIdx.x * 8 + (t >> 5);
    if (node >= NN) return;
    int sub = t & 31;
    int c = sub & 15;
    int e2 = sub >> 4;
    int beg = offs[node], end = offs[node + 1];
    float acc = 0.f;
    int i = beg + e2;
    for (; i + 6 < end; i += 8) {
        int s0 = ssrc[i], s1 = ssrc[i + 2], s2 = ssrc[i + 4], s3 = ssrc[i + 6];
        float h0 = H2[(size_t)s0 * 10 + c];
        float h1 = H2[(size_t)s1 * 10 + c];
        float h2 = H2[(size_t)s2 * 10 + c];
        float h3 = H2[(size_t)s3 * 10 + c];
        acc += (h0 + h1) + (h2 + h3);
    }
    for (; i < end; i += 2) acc += H2[(size_t)ssrc[i] * 10 + c];
    if (e2 == 0) acc += H2[(size_t)node * 10 + c];   // self loop (pre-scaled)
    acc += __shfl_xor(acc, 16, 64);
    if (sub < 10) {
        float dn = dinv[node];
        H2act[(size_t)node * 10 + c] = elu(fmaf(dn, acc, b2[c]));
    }
}

// ---------- per-graph mean pool + log_softmax (no atomics) ----------
__global__ __launch_bounds__(320) void pool_final_kernel(
    const float* __restrict__ H2act, const int* __restrict__ gstart,
    float* __restrict__ out, int NG) {
    __shared__ float red[32][10];
    __shared__ float m[10];
    __shared__ float s_lse;
    int g = blockIdx.x;
    int t = threadIdx.x;
    int grp = t / 10;
    int c = t - grp * 10;
    int lo = gstart[g], hi = gstart[g + 1];
    float acc = 0.f;
    if (grp < 32) {
        for (int n = lo + grp; n < hi; n += 32) acc += H2act[(size_t)n * 10 + c];
        red[grp][c] = acc;
    }
    __syncthreads();
    if (t < 10) {
        float s = 0.f;
        #pragma unroll
        for (int j = 0; j < 32; ++j) s += red[j][t];
        m[t] = s / fmaxf((float)(hi - lo), 1.0f);
    }
    __syncthreads();
    if (t == 0) {
        float mx = -1e30f;
        for (int c2 = 0; c2 < 10; ++c2) mx = fmaxf(mx, m[c2]);
        float s = 0.f;
        for (int c2 = 0; c2 < 10; ++c2) s += expf(m[c2] - mx);
        s_lse = logf(s) + mx;
    }
    __syncthreads();
    if (t < 10) out[g * 10 + t] = m[t] - s_lse;
}

extern "C" void kernel_launch(void* const* d_in, const int* in_sizes, int n_in,
                              void* d_out, int out_size, void* d_ws, size_t ws_size,
                              hipStream_t stream) {
    const float* x     = (const float*)d_in[0];
    const int*   eidx  = (const int*)d_in[1];
    const int*   batch = (const int*)d_in[2];
    const float* W1    = (const float*)d_in[3];
    const float* b1    = (const float*)d_in[4];
    const float* W2    = (const float*)d_in[5];
    const float* b2    = (const float*)d_in[6];

    int NN = in_sizes[0] / 256;     // 50000
    int E  = in_sizes[1] / 2;       // 1600000
    int NG = out_size / 10;         // 64
    const int* src = eidx;
    const int* dst = eidx + E;

    char* ws = (char*)d_ws;
    size_t off = 0;
    auto alloc = [&](size_t bytes) -> void* {
        void* p = ws + off;
        off += (bytes + 255) & ~((size_t)255);
        return p;
    };
    int*    cnt      = (int*)alloc((size_t)NN * 4);
    int*    offs     = (int*)alloc((size_t)(NN + 1) * 4);
    int*    cursor   = (int*)alloc((size_t)NN * 4);
    int*    partials = (int*)alloc(256 * 4);
    int*    pscan    = (int*)alloc(256 * 4);
    float*  dinv     = (float*)alloc((size_t)NN * 4);
    int*    gstart   = (int*)alloc((size_t)(NG + 1) * 4);
    ushort* W1T      = (ushort*)alloc((size_t)256 * 256 * 2);
    int*    ssrc     = (int*)alloc((size_t)E * 4);
    ushort* H1       = (ushort*)alloc((size_t)NN * 256 * 2);
    float*  H2       = (float*)alloc((size_t)NN * 10 * 4);
    float*  H2act    = (float*)alloc((size_t)NN * 10 * 4);

    hipMemsetAsync(cnt, 0, (size_t)NN * 4, stream);

    int nb = (NN + 255) / 256;
    count_kernel  <<<1024, 256, 0, stream>>>(dst, E, cnt);
    scan1_kernel  <<<nb, 256, 0, stream>>>(cnt, NN, partials);
    scan2_kernel  <<<1, 64, 0, stream>>>(partials, nb, pscan);
    scan3_kernel  <<<nb, 256, 0, stream>>>(cnt, NN, pscan, offs, cursor, dinv);
    scatter_kernel<<<2048, 256, 0, stream>>>(src, dst, E, cursor, ssrc, NN);
    gstart_kernel <<<1, 128, 0, stream>>>(batch, NN, NG, gstart);
    wtrans_kernel <<<16, 256, 0, stream>>>(W1, W1T);
    gemm1_mfma_kernel<<<(NN + 63) / 64, 256, 0, stream>>>(x, W1T, dinv, H1, NN);
    agg1_gemm2_kernel<<<(NN + 3) / 4, 256, 0, stream>>>(H1, offs, ssrc, dinv, b1, W2, H2, NN);
    agg2_elu_kernel  <<<(NN + 7) / 8, 256, 0, stream>>>(H2, offs, ssrc, dinv, b2, H2act, NN);
    pool_final_kernel<<<NG, 320, 0, stream>>>(H2act, gstart, (float*)d_out, NG);
}